// Round 4
// baseline (3446.297 us; speedup 1.0000x reference)
//
#include <hip/hip_runtime.h>

typedef long long i64;
#define CDIV(a,b) (((a)+(b)-1)/(b))

#define NN   20000
#define RRN  256
#define BB   4
#define LLAY 4

// ---------------- utility fills ----------------
__global__ void k_fillf(float* p, float v, int n){ int i=blockIdx.x*256+threadIdx.x; if(i<n) p[i]=v; }
__global__ void k_fill2i(int* p1, int n1, int* p2, int n2){
  int i=blockIdx.x*256+threadIdx.x;
  if(i<n1) p1[i]=0;
  if(i<n2) p2[i]=0;
}

// ---------------- CSR build: entity graph ----------------
__global__ void k_hist_ent(const int* __restrict__ dst, int* __restrict__ cnt, int E){
  int e=blockIdx.x*256+threadIdx.x; if(e<E) atomicAdd(&cnt[dst[e]],1);
}
__global__ void k_scan_ent(int* cnt_cur, int* rp, int n){
  __shared__ int sm[1024];
  __shared__ int carry;
  int tx=threadIdx.x;
  if(tx==0) carry=0;
  __syncthreads();
  for(int base=0;base<n;base+=1024){
    int i=base+tx;
    int val=(i<n)?cnt_cur[i]:0;
    sm[tx]=val; __syncthreads();
    for(int off=1;off<1024;off<<=1){
      int t=(tx>=off)?sm[tx-off]:0; __syncthreads();
      sm[tx]+=t; __syncthreads();
    }
    int excl=carry+sm[tx]-val;
    if(i<n){ rp[i]=excl; cnt_cur[i]=excl; }
    __syncthreads();
    if(tx==0) carry+=sm[1023];
    __syncthreads();
  }
  if(tx==0) rp[n]=carry;
}
__global__ void k_fill_ent(const int* __restrict__ src, const int* __restrict__ dst,
                           int* __restrict__ cur, int* __restrict__ colsrc, int E){
  int e=blockIdx.x*256+threadIdx.x;
  if(e<E){ int p=atomicAdd(&cur[dst[e]],1); colsrc[p]=src[e]; }
}

// ---------------- CSR build: relation graph (4 directions) ----------------
__global__ void k_hist_rel(const int* __restrict__ rei, int* __restrict__ cnt, int ER){
  int e=blockIdx.x*256+threadIdx.x; int d=blockIdx.y;
  if(e<ER) atomicAdd(&cnt[d*256 + rei[(i64)(2*d+1)*ER + e]],1);
}
__global__ void k_scan_rel(int* cnt_cur, int* rp){
  __shared__ int sm[256];
  int d=blockIdx.x, tx=threadIdx.x;
  int val=cnt_cur[d*256+tx];
  sm[tx]=val; __syncthreads();
  for(int off=1;off<256;off<<=1){
    int t=(tx>=off)?sm[tx-off]:0; __syncthreads();
    sm[tx]+=t; __syncthreads();
  }
  int excl=sm[tx]-val;
  rp[d*257+tx]=excl;
  cnt_cur[d*256+tx]=excl;
  if(tx==255) rp[d*257+256]=sm[255];
}
__global__ void k_fill_rel(const int* __restrict__ rei, int* __restrict__ cur,
                           int* __restrict__ colr, int ER){
  int e=blockIdx.x*256+threadIdx.x; int d=blockIdx.y;
  if(e<ER){
    int dst=rei[(i64)(2*d+1)*ER+e];
    int p=atomicAdd(&cur[d*256+dst],1);
    colr[d*ER+p]=e;
  }
}

// ---------------- x init (layout [n][b][64]) ----------------
__global__ void k_init_x(float* __restrict__ x, const int* __restrict__ batch, int N){
  int i=blockIdx.x*256+threadIdx.x;          // float4 index
  int total=N*64;
  if(i>=total) return;
  int n=i>>6; int b=(i>>4)&3;
  int h=batch[b*96], t=batch[b*96+1];
  float bnd=(n==h?1.f:0.f)-(n==t?1.f:0.f);
  ((float4*)x)[i]=make_float4(bnd,bnd,bnd,bnd);
}

// ---------------- all entity per-layer rel vectors: v[l] = mlp2_l(ones), grid=LLAY ----------------
__global__ void k_ventity_all(const float* __restrict__ W1, const float* __restrict__ b1,
                              const float* __restrict__ W2, const float* __restrict__ b2,
                              float* __restrict__ v){
  __shared__ float sh[64];
  int l=blockIdx.x;
  const float* W1l=W1+(i64)l*4096;
  const float* W2l=W2+(i64)l*4096;
  int j=threadIdx.x;
  float s=b1[l*64+j];
  for(int i=0;i<64;i++) s+=W1l[i*64+j];
  sh[j]=fmaxf(s,0.f);
  __syncthreads();
  float vd=b2[l*64+j];
  for(int k=0;k<64;k++) vd+=sh[k]*W2l[k*64+j];
  v[l*64+j]=vd;
}

// ---------------- adjusted bias for final MLP ([x|ones] @ W1) ----------------
__global__ void k_badj(const float* __restrict__ W1, const float* __restrict__ b1,
                       float* __restrict__ badj){
  int j=threadIdx.x; // 128
  float s=b1[j];
  for(int k=0;k<64;k++) s+=W1[(64+k)*128+j];
  badj[j]=s;
}

// ---------------- entity SpMM: agg = (A @ x) * v + boundary ----------------
__global__ __launch_bounds__(256) void k_spmm_ent(
    const float* __restrict__ x, const float* __restrict__ v,
    const int* __restrict__ rp, const int* __restrict__ col,
    const int* __restrict__ batch, float* __restrict__ agg, int N){
  int gw=blockIdx.x*4+(threadIdx.x>>6);
  int lane=threadIdx.x&63;
  if(gw>=N) return;
  int n=gw;
  int beg=rp[n], end=rp[n+1];
  float a0=0.f,a1=0.f,a2=0.f,a3=0.f;
  int e=beg;
  for(; e+2<=end; e+=2){
    int s0=col[e], s1=col[e+1];
    const float* r0=x+(i64)s0*256;
    const float* r1=x+(i64)s1*256;
    a0+=r0[lane];     a1+=r0[64+lane];
    a2+=r0[128+lane]; a3+=r0[192+lane];
    a0+=r1[lane];     a1+=r1[64+lane];
    a2+=r1[128+lane]; a3+=r1[192+lane];
  }
  if(e<end){
    const float* r0=x+(i64)col[e]*256;
    a0+=r0[lane]; a1+=r0[64+lane]; a2+=r0[128+lane]; a3+=r0[192+lane];
  }
  float vl=v[lane];
  #pragma unroll
  for(int b=0;b<4;b++){
    int h=batch[b*96], t=batch[b*96+1];
    float bnd=(n==h?1.f:0.f)-(n==t?1.f:0.f);
    float av=(b==0)?a0:(b==1)?a1:(b==2)?a2:a3;
    agg[((i64)n*4+b)*64+lane]=av*vl+bnd;
  }
}

// ---------------- relation SpMM, 1 direction, 4 edge-chunks, atomic into aggr ----------------
// aggr[d] pre-filled with 1.0 (boundary_r); grid (256 rows, 4 chunks)
__global__ __launch_bounds__(256) void k_spmm_rel(
    const float* __restrict__ y, const float* __restrict__ relbuf,
    const int* __restrict__ rp_rel, const int* __restrict__ col_rel,
    const int* __restrict__ rei, const int* __restrict__ ret,
    float* __restrict__ aggr, int d, int ER){
  __shared__ float s_acc[4][4][64];
  int rr=blockIdx.x; int ch=blockIdx.y;
  int tx=threadIdx.x; int ws=tx>>6; int lane=tx&63;
  int beg=rp_rel[d*257+rr], end=rp_rel[d*257+rr+1];
  int len=end-beg;
  int per=(len+3)>>2;
  int cb=beg+ch*per;
  int ce_=cb+per; if(ce_>end) ce_=end;
  int clen=ce_-cb; if(clen<0) clen=0;
  int perw=(clen+3)>>2;
  int e0=cb+ws*perw;
  int e1=e0+perw; if(e1>ce_) e1=ce_;
  const int* cidx=col_rel+(i64)d*ER;
  const int* srcA=rei+(i64)(2*d)*ER;
  const int* etA=ret+(i64)d*ER;
  float a0=0.f,a1=0.f,a2=0.f,a3=0.f;
  for(int e=e0;e<e1;++e){
    int eid=cidx[e];
    int s=srcA[eid], t=etA[eid];
    const float* yr=y+(i64)s*64;          // y layout [b][r][64], b stride 16384
    const float* rr2=relbuf+(i64)t*256;   // relbuf layout [n][b][64]
    a0+=yr[0*16384+lane]*rr2[     lane];
    a1+=yr[1*16384+lane]*rr2[ 64+lane];
    a2+=yr[2*16384+lane]*rr2[128+lane];
    a3+=yr[3*16384+lane]*rr2[192+lane];
  }
  s_acc[ws][0][lane]=a0; s_acc[ws][1][lane]=a1;
  s_acc[ws][2][lane]=a2; s_acc[ws][3][lane]=a3;
  __syncthreads();
  int b=ws;
  float vv=s_acc[0][b][lane]+s_acc[1][b][lane]+s_acc[2][b][lane]+s_acc[3][b][lane];
  atomicAdd(&aggr[((i64)(d*4+b)*256+rr)*64+lane],vv);
}

// ---------------- generic 64-col GEMM: out = op(relu?(in@W + bias)) ----------------
// OP: 0=write, 1=add residual then write
template<int KC, bool RELU, int OP>
__global__ __launch_bounds__(256) void k_gemm64(
    const float* __restrict__ inA, int lda,
    const float* __restrict__ inB, int ldb, i64 inBs,
    const float* __restrict__ W, int ldw, i64 Ws,
    const float* __restrict__ bias, i64 biasS,
    float* out, int ldo, i64 outS,
    const float* resid, int ldr,
    int rows){
  __shared__ float s_in[128*68];
  __shared__ float s_wt[64*68];
  int tx=threadIdx.x;
  int dy=blockIdx.y;
  const float* Wd=W+(i64)dy*Ws;
  const float* biasd=bias+(i64)dy*biasS;
  float* outd=out+(i64)dy*outS;
  int row0=blockIdx.x*128;
  int rslot=tx>>4, c0=tx&15;
  float acc[8][4];
  #pragma unroll
  for(int j=0;j<8;j++)
    #pragma unroll
    for(int cc=0;cc<4;cc++) acc[j][cc]=0.f;
  for(int kc=0;kc<KC;++kc){
    const float* in=(kc==0)?inA:(inB+(i64)dy*inBs);
    int ld=(kc==0)?lda:ldb;
    #pragma unroll
    for(int i=0;i<8;i++){
      int id=i*256+tx;
      int r=id>>4, k4=id&15;
      int gr=row0+r;
      float4 val=make_float4(0.f,0.f,0.f,0.f);
      if(gr<rows) val=*(const float4*)(in+(i64)gr*ld+k4*4);
      *(float4*)&s_in[r*68+k4*4]=val;
    }
    #pragma unroll
    for(int i=0;i<4;i++){
      int id=i*256+tx;
      int k=id>>4, c4=(id&15)*4;
      float4 wv=*(const float4*)(Wd+(i64)(kc*64+k)*ldw+c4);
      s_wt[(c4+0)*68+k]=wv.x; s_wt[(c4+1)*68+k]=wv.y;
      s_wt[(c4+2)*68+k]=wv.z; s_wt[(c4+3)*68+k]=wv.w;
    }
    __syncthreads();
    #pragma unroll
    for(int k4=0;k4<16;k4++){
      float4 wv[4];
      #pragma unroll
      for(int cc=0;cc<4;cc++) wv[cc]=*(const float4*)&s_wt[(c0+16*cc)*68+k4*4];
      #pragma unroll
      for(int j=0;j<8;j++){
        float4 iv=*(const float4*)&s_in[(rslot+16*j)*68+k4*4];
        #pragma unroll
        for(int cc=0;cc<4;cc++)
          acc[j][cc]+=iv.x*wv[cc].x+iv.y*wv[cc].y+iv.z*wv[cc].z+iv.w*wv[cc].w;
      }
    }
    __syncthreads();
  }
  #pragma unroll
  for(int j=0;j<8;j++){
    int r=row0+rslot+16*j;
    if(r>=rows) continue;
    #pragma unroll
    for(int cc=0;cc<4;cc++){
      int c=c0+16*cc;
      float vv=acc[j][cc]+biasd[c];
      if(RELU) vv=fmaxf(vv,0.f);
      if(OP==1) vv+=resid[(i64)r*ldr+c];
      outd[(i64)r*ldo+c]=vv;
    }
  }
}

// ---------------- fused 64->64(relu)->64 MLP, 128-row tiles ----------------
// s_in is reused for the hidden activations after GEMM1 (52.2 KB LDS total).
__global__ __launch_bounds__(256) void k_mlp128(
    const float* __restrict__ in,
    const float* __restrict__ W1,
    const float* __restrict__ b1,
    const float* __restrict__ W2,
    const float* __restrict__ b2,
    float* __restrict__ out,
    int rows){
  __shared__ float s_in[128*68];
  __shared__ float s_wt[64*68];
  int tx=threadIdx.x;
  int row0=blockIdx.x*128;
  int rslot=tx>>4, c0=tx&15;
  // stage input tile (128 x 64)
  #pragma unroll
  for(int i=0;i<8;i++){
    int id=i*256+tx;
    int r=id>>4, k4=id&15;
    int gr=row0+r;
    float4 val=make_float4(0.f,0.f,0.f,0.f);
    if(gr<rows) val=*(const float4*)(in+(i64)gr*64+k4*4);
    *(float4*)&s_in[r*68+k4*4]=val;
  }
  // stage W1 transposed: s_wt[c][k]
  #pragma unroll
  for(int i=0;i<4;i++){
    int id=i*256+tx;
    int k=id>>4, c4=(id&15)*4;
    float4 wv=*(const float4*)(W1+(i64)k*64+c4);
    s_wt[(c4+0)*68+k]=wv.x; s_wt[(c4+1)*68+k]=wv.y;
    s_wt[(c4+2)*68+k]=wv.z; s_wt[(c4+3)*68+k]=wv.w;
  }
  __syncthreads();
  float acc[8][4];
  #pragma unroll
  for(int j=0;j<8;j++)
    #pragma unroll
    for(int cc=0;cc<4;cc++) acc[j][cc]=0.f;
  #pragma unroll
  for(int k4=0;k4<16;k4++){
    float4 wv[4];
    #pragma unroll
    for(int cc=0;cc<4;cc++) wv[cc]=*(const float4*)&s_wt[(c0+16*cc)*68+k4*4];
    #pragma unroll
    for(int j=0;j<8;j++){
      float4 iv=*(const float4*)&s_in[(rslot+16*j)*68+k4*4];
      #pragma unroll
      for(int cc=0;cc<4;cc++)
        acc[j][cc]+=iv.x*wv[cc].x+iv.y*wv[cc].y+iv.z*wv[cc].z+iv.w*wv[cc].w;
    }
  }
  __syncthreads();   // all reads of s_in / s_wt complete
  // hidden = relu(acc + b1) -> overwrite s_in; stage W2 -> s_wt
  #pragma unroll
  for(int j=0;j<8;j++)
    #pragma unroll
    for(int cc=0;cc<4;cc++)
      s_in[(rslot+16*j)*68+(c0+16*cc)]=fmaxf(acc[j][cc]+b1[c0+16*cc],0.f);
  #pragma unroll
  for(int i=0;i<4;i++){
    int id=i*256+tx;
    int k=id>>4, c4=(id&15)*4;
    float4 wv=*(const float4*)(W2+(i64)k*64+c4);
    s_wt[(c4+0)*68+k]=wv.x; s_wt[(c4+1)*68+k]=wv.y;
    s_wt[(c4+2)*68+k]=wv.z; s_wt[(c4+3)*68+k]=wv.w;
  }
  __syncthreads();
  #pragma unroll
  for(int j=0;j<8;j++)
    #pragma unroll
    for(int cc=0;cc<4;cc++) acc[j][cc]=0.f;
  #pragma unroll
  for(int k4=0;k4<16;k4++){
    float4 wv[4];
    #pragma unroll
    for(int cc=0;cc<4;cc++) wv[cc]=*(const float4*)&s_wt[(c0+16*cc)*68+k4*4];
    #pragma unroll
    for(int j=0;j<8;j++){
      float4 iv=*(const float4*)&s_in[(rslot+16*j)*68+k4*4];
      #pragma unroll
      for(int cc=0;cc<4;cc++)
        acc[j][cc]+=iv.x*wv[cc].x+iv.y*wv[cc].y+iv.z*wv[cc].z+iv.w*wv[cc].w;
    }
  }
  #pragma unroll
  for(int j=0;j<8;j++){
    int r=row0+rslot+16*j;
    if(r>=rows) continue;
    #pragma unroll
    for(int cc=0;cc<4;cc++)
      out[(i64)r*64+c0+16*cc]=acc[j][cc]+b2[c0+16*cc];
  }
}

// ---------------- fused final entity MLP: x <- mlp2_128([x|ones]) in-place ----------------
__global__ __launch_bounds__(256) void k_mlp_ent(
    float* __restrict__ x,
    const float* __restrict__ W1,   // (128,128) row-major; rows 0..63 used
    const float* __restrict__ badj, // 128 (ones-half + b1 folded)
    const float* __restrict__ W2,   // (128,64) row-major
    const float* __restrict__ b2o,  // 64
    int rows){
  __shared__ float s_in[64*68];
  __shared__ float s_h[64*68];
  __shared__ float s_wt[64*68];
  int tx=threadIdx.x;
  int row0=blockIdx.x*64;
  int rslot=tx>>4, c0=tx&15;
  #pragma unroll
  for(int i=0;i<4;i++){
    int id=i*256+tx;
    int r=id>>4, k4=id&15;
    int gr=row0+r;
    float4 val=make_float4(0.f,0.f,0.f,0.f);
    if(gr<rows) val=*(const float4*)(x+(i64)gr*64+k4*4);
    *(float4*)&s_in[r*68+k4*4]=val;
  }
  float accO[4][4];
  #pragma unroll
  for(int j=0;j<4;j++)
    #pragma unroll
    for(int cc=0;cc<4;cc++) accO[j][cc]=0.f;
  for(int half=0;half<2;++half){
    __syncthreads();
    #pragma unroll
    for(int i=0;i<4;i++){
      int id=i*256+tx;
      int k=id>>4, c4=(id&15)*4;
      float4 wv=*(const float4*)(W1+(i64)k*128+half*64+c4);
      s_wt[(c4+0)*68+k]=wv.x; s_wt[(c4+1)*68+k]=wv.y;
      s_wt[(c4+2)*68+k]=wv.z; s_wt[(c4+3)*68+k]=wv.w;
    }
    __syncthreads();
    float acc[4][4];
    #pragma unroll
    for(int j=0;j<4;j++)
      #pragma unroll
      for(int cc=0;cc<4;cc++) acc[j][cc]=0.f;
    #pragma unroll
    for(int k4=0;k4<16;k4++){
      float4 wv[4];
      #pragma unroll
      for(int cc=0;cc<4;cc++) wv[cc]=*(const float4*)&s_wt[(c0+16*cc)*68+k4*4];
      #pragma unroll
      for(int j=0;j<4;j++){
        float4 iv=*(const float4*)&s_in[(rslot+16*j)*68+k4*4];
        #pragma unroll
        for(int cc=0;cc<4;cc++)
          acc[j][cc]+=iv.x*wv[cc].x+iv.y*wv[cc].y+iv.z*wv[cc].z+iv.w*wv[cc].w;
      }
    }
    __syncthreads();
    #pragma unroll
    for(int j=0;j<4;j++)
      #pragma unroll
      for(int cc=0;cc<4;cc++)
        s_h[(rslot+16*j)*68+(c0+16*cc)]=fmaxf(acc[j][cc]+badj[half*64+c0+16*cc],0.f);
    #pragma unroll
    for(int i=0;i<4;i++){
      int id=i*256+tx;
      int k=id>>4, c4=(id&15)*4;
      float4 wv=*(const float4*)(W2+(i64)(half*64+k)*64+c4);
      s_wt[(c4+0)*68+k]=wv.x; s_wt[(c4+1)*68+k]=wv.y;
      s_wt[(c4+2)*68+k]=wv.z; s_wt[(c4+3)*68+k]=wv.w;
    }
    __syncthreads();
    #pragma unroll
    for(int k4=0;k4<16;k4++){
      float4 wv[4];
      #pragma unroll
      for(int cc=0;cc<4;cc++) wv[cc]=*(const float4*)&s_wt[(c0+16*cc)*68+k4*4];
      #pragma unroll
      for(int j=0;j<4;j++){
        float4 iv=*(const float4*)&s_h[(rslot+16*j)*68+k4*4];
        #pragma unroll
        for(int cc=0;cc<4;cc++)
          accO[j][cc]+=iv.x*wv[cc].x+iv.y*wv[cc].y+iv.z*wv[cc].z+iv.w*wv[cc].w;
      }
    }
  }
  #pragma unroll
  for(int j=0;j<4;j++){
    int r=row0+rslot+16*j;
    if(r>=rows) continue;
    #pragma unroll
    for(int cc=0;cc<4;cc++)
      x[(i64)r*64+c0+16*cc]=accO[j][cc]+b2o[cc*16+c0-(cc*16+c0)+c0+16*cc];
  }
}

// ---------------- y += sum of 4 per-direction hid buffers; reset aggr to 1.0 ----------------
__global__ void k_yupd_fill(float* __restrict__ y, const float* __restrict__ h,
                            float* __restrict__ aggr){
  int i=blockIdx.x*256+threadIdx.x;   // grid covers 262144
  if(i<65536) y[i]+=h[i]+h[65536+i]+h[131072+i]+h[196608+i];
  if(i<262144) aggr[i]=1.0f;
}

// ---------------- init y=1 and aggr=1 ----------------
__global__ void k_init_rel(float* __restrict__ y, float* __restrict__ aggr){
  int i=blockIdx.x*256+threadIdx.x;
  if(i<65536) y[i]=1.0f;
  if(i<262144) aggr[i]=1.0f;
}

// ---------------- final gather + trix MLP ----------------
__global__ __launch_bounds__(256) void k_trix(
    const float* __restrict__ y, const int* __restrict__ batch,
    const float* __restrict__ W1, const float* __restrict__ b1,
    const float* __restrict__ W2, const float* __restrict__ b2,
    float* __restrict__ out){
  __shared__ float s_w1[64*65];
  int tx=threadIdx.x;
  for(int i=tx;i<4096;i+=256){
    int k=i>>6, j=i&63;
    s_w1[k*65+j]=W1[i];
  }
  __syncthreads();
  int wave=tx>>6, lane=tx&63;
  for(int row=wave;row<128;row+=4){
    int b=row>>5, i=row&31;
    int ridx=batch[b*96+i*3+2];
    const float* f=y+((i64)b*256+ridx)*64;
    float hj=b1[lane];
    for(int k=0;k<64;k++) hj+=f[k]*s_w1[k*65+lane];
    hj=fmaxf(hj,0.f);
    float contrib=hj*W2[lane];
    for(int off=32;off;off>>=1) contrib+=__shfl_down(contrib,off);
    if(lane==0) out[row]=contrib+b2[0];
  }
}

extern "C" void kernel_launch(void* const* d_in, const int* in_sizes, int n_in,
                              void* d_out, int out_size, void* d_ws, size_t ws_size,
                              hipStream_t stream){
  const int* batch=(const int*)d_in[0];
  const int* eei  =(const int*)d_in[1];
  const int* rei  =(const int*)d_in[3];
  const int* ret  =(const int*)d_in[4];
  const float* entW1=(const float*)d_in[7];
  const float* entb1=(const float*)d_in[8];
  const float* entW2=(const float*)d_in[9];
  const float* entb2=(const float*)d_in[10];
  const float* entWl=(const float*)d_in[11];
  const float* entbl=(const float*)d_in[12];
  const float* relW1=(const float*)d_in[13];
  const float* relb1=(const float*)d_in[14];
  const float* relW2=(const float*)d_in[15];
  const float* relb2=(const float*)d_in[16];
  const float* relWl=(const float*)d_in[17];
  const float* relbl=(const float*)d_in[18];
  const float* mW1=(const float*)d_in[19];
  const float* mb1=(const float*)d_in[20];
  const float* mW2=(const float*)d_in[21];
  const float* mb2=(const float*)d_in[22];
  const float* tW1=(const float*)d_in[23];
  const float* tb1=(const float*)d_in[24];
  const float* tW2=(const float*)d_in[25];
  const float* tb2=(const float*)d_in[26];
  const int E =in_sizes[2];
  const int ER=in_sizes[4]/4;
  float* out=(float*)d_out;

  // workspace layout (floats)
  float* ws=(float*)d_ws;
  float* x     =ws;                   // 5,120,000  ([n][b][64]); becomes node_reps
  float* buf   =x+5120000;            // 5,120,000  entity agg; rel relbuf (1 dir)
  float* aggr  =buf+5120000;          //   262,144  rel agg [d][b][256][64]
  float* hidr  =aggr+262144;          //   262,144  rel hid per-direction
  float* y     =hidr+262144;          //    65,536  [b][256][64]
  float* v     =y+65536;              //       256  (4 layers x 64)
  float* badj  =v+256;                //       128
  int* rp_ent =(int*)(badj+128);      // NN+1
  int* cur_ent=rp_ent+NN+1;           // NN
  int* col_ent=cur_ent+NN;            // E
  int* rp_rel =col_ent+E;             // 4*257
  int* cur_rel=rp_rel+4*257;          // 1024
  int* col_rel=cur_rel+1024;          // 4*ER

  size_t needed=(size_t)10830464*4 + (size_t)(NN+1+NN+E+4*257+1024+4*ER)*4;
  if(ws_size<needed) return; // insufficient scratch; validation will flag

  const int* esrc=eei;
  const int* edst=eei+E;

  // ---- CSR builds ----
  k_fill2i<<<CDIV(NN,256),256,0,stream>>>(cur_ent,NN,cur_rel,1024);
  k_hist_ent<<<CDIV(E,256),256,0,stream>>>(edst,cur_ent,E);
  k_scan_ent<<<1,1024,0,stream>>>(cur_ent,rp_ent,NN);
  k_fill_ent<<<CDIV(E,256),256,0,stream>>>(esrc,edst,cur_ent,col_ent,E);
  k_hist_rel<<<dim3(CDIV(ER,256),4),256,0,stream>>>(rei,cur_rel,ER);
  k_scan_rel<<<4,256,0,stream>>>(cur_rel,rp_rel);
  k_fill_rel<<<dim3(CDIV(ER,256),4),256,0,stream>>>(rei,cur_rel,col_rel,ER);

  // ---- precompute per-layer v and adjusted bias ----
  k_ventity_all<<<LLAY,64,0,stream>>>(entW1,entb1,entW2,entb2,v);
  k_badj<<<1,128,0,stream>>>(mW1,mb1,badj);

  // ---- entity stack ----
  k_init_x<<<CDIV(NN*64,256),256,0,stream>>>(x,batch,NN);
  for(int l=0;l<LLAY;l++){
    k_spmm_ent<<<CDIV(NN,4),256,0,stream>>>(x,v+(i64)l*64,rp_ent,col_ent,batch,buf,NN);
    k_gemm64<2,true,1><<<625,256,0,stream>>>(x,64, buf,64,0,
        entWl+(i64)l*8192,64,0, entbl+(i64)l*64,0, x,64,0, x,64, 80000);
  }
  // ---- final entity MLP (fused, in-place): x <- node_reps ----
  k_mlp_ent<<<1250,256,0,stream>>>(x,mW1,badj,mW2,mb2,80000);

  // ---- relation stack ----
  k_init_rel<<<1024,256,0,stream>>>(y,aggr);
  for(int l=0;l<LLAY;l++){
    for(int d=0;d<4;d++){
      k_mlp128<<<625,256,0,stream>>>(x,
          relW1+(i64)(d*LLAY+l)*4096, relb1+(i64)(d*LLAY+l)*64,
          relW2+(i64)(d*LLAY+l)*4096, relb2+(i64)(d*LLAY+l)*64,
          buf, 80000);
      k_spmm_rel<<<dim3(256,4),256,0,stream>>>(y,buf,rp_rel,col_rel,rei,ret,aggr,d,ER);
    }
    k_gemm64<2,true,0><<<dim3(8,4),256,0,stream>>>(y,64, aggr,64,(i64)65536,
        relWl+(i64)l*8192,64,(i64)LLAY*8192, relbl+(i64)l*64,(i64)LLAY*64,
        hidr,64,(i64)65536, y,64, 1024);
    k_yupd_fill<<<1024,256,0,stream>>>(y,hidr,aggr);
  }

  // ---- score ----
  k_trix<<<1,256,0,stream>>>(y,batch,tW1,tb1,tW2,tb2,out);
}

// Round 6
// 1324.419 us; speedup vs baseline: 2.6021x; 2.6021x over previous
//
#include <hip/hip_runtime.h>

typedef long long i64;
#define CDIV(a,b) (((a)+(b)-1)/(b))

#define NN   20000
#define RRN  256
#define BB   4
#define LLAY 4

// ---------------- utility fills ----------------
__global__ void k_fill2i(int* p1, int n1, int* p2, int n2){
  int i=blockIdx.x*256+threadIdx.x;
  if(i<n1) p1[i]=0;
  if(i<n2) p2[i]=0;
}

// ---------------- CSR build: entity graph ----------------
__global__ void k_hist_ent(const int* __restrict__ dst, int* __restrict__ cnt, int E){
  int e=blockIdx.x*256+threadIdx.x; if(e<E) atomicAdd(&cnt[dst[e]],1);
}
__global__ void k_scan_ent(int* cnt_cur, int* rp, int n){
  __shared__ int sm[1024];
  __shared__ int carry;
  int tx=threadIdx.x;
  if(tx==0) carry=0;
  __syncthreads();
  for(int base=0;base<n;base+=1024){
    int i=base+tx;
    int val=(i<n)?cnt_cur[i]:0;
    sm[tx]=val; __syncthreads();
    for(int off=1;off<1024;off<<=1){
      int t=(tx>=off)?sm[tx-off]:0; __syncthreads();
      sm[tx]+=t; __syncthreads();
    }
    int excl=carry+sm[tx]-val;
    if(i<n){ rp[i]=excl; cnt_cur[i]=excl; }
    __syncthreads();
    if(tx==0) carry+=sm[1023];
    __syncthreads();
  }
  if(tx==0) rp[n]=carry;
}
__global__ void k_fill_ent(const int* __restrict__ src, const int* __restrict__ dst,
                           int* __restrict__ cur, int* __restrict__ colsrc, int E){
  int e=blockIdx.x*256+threadIdx.x;
  if(e<E){ int p=atomicAdd(&cur[dst[e]],1); colsrc[p]=src[e]; }
}

// ---------------- CSR build: relation graph (4 directions) ----------------
__global__ void k_hist_rel(const int* __restrict__ rei, int* __restrict__ cnt, int ER){
  int e=blockIdx.x*256+threadIdx.x; int d=blockIdx.y;
  if(e<ER) atomicAdd(&cnt[d*256 + rei[(i64)(2*d+1)*ER + e]],1);
}
__global__ void k_scan_rel(int* cnt_cur, int* rp){
  __shared__ int sm[256];
  int d=blockIdx.x, tx=threadIdx.x;
  int val=cnt_cur[d*256+tx];
  sm[tx]=val; __syncthreads();
  for(int off=1;off<256;off<<=1){
    int t=(tx>=off)?sm[tx-off]:0; __syncthreads();
    sm[tx]+=t; __syncthreads();
  }
  int excl=sm[tx]-val;
  rp[d*257+tx]=excl;
  cnt_cur[d*256+tx]=excl;
  if(tx==255) rp[d*257+256]=sm[255];
}
__global__ void k_fill_rel(const int* __restrict__ rei, int* __restrict__ cur,
                           int* __restrict__ colr, int ER){
  int e=blockIdx.x*256+threadIdx.x; int d=blockIdx.y;
  if(e<ER){
    int dst=rei[(i64)(2*d+1)*ER+e];
    int p=atomicAdd(&cur[d*256+dst],1);
    colr[d*ER+p]=e;
  }
}

// ---------------- x init (layout [n][b][64]) ----------------
__global__ void k_init_x(float* __restrict__ x, const int* __restrict__ batch, int N){
  int i=blockIdx.x*256+threadIdx.x;          // float4 index
  int total=N*64;
  if(i>=total) return;
  int n=i>>6; int b=(i>>4)&3;
  int h=batch[b*96], t=batch[b*96+1];
  float bnd=(n==h?1.f:0.f)-(n==t?1.f:0.f);
  ((float4*)x)[i]=make_float4(bnd,bnd,bnd,bnd);
}

// ---------------- all entity per-layer rel vectors: v[l] = mlp2_l(ones), grid=LLAY ----------------
__global__ void k_ventity_all(const float* __restrict__ W1, const float* __restrict__ b1,
                              const float* __restrict__ W2, const float* __restrict__ b2,
                              float* __restrict__ v){
  __shared__ float sh[64];
  int l=blockIdx.x;
  const float* W1l=W1+(i64)l*4096;
  const float* W2l=W2+(i64)l*4096;
  int j=threadIdx.x;
  float s=b1[l*64+j];
  for(int i=0;i<64;i++) s+=W1l[i*64+j];
  sh[j]=fmaxf(s,0.f);
  __syncthreads();
  float vd=b2[l*64+j];
  for(int k=0;k<64;k++) vd+=sh[k]*W2l[k*64+j];
  v[l*64+j]=vd;
}

// ---------------- adjusted bias for final MLP ([x|ones] @ W1) ----------------
__global__ void k_badj(const float* __restrict__ W1, const float* __restrict__ b1,
                       float* __restrict__ badj){
  int j=threadIdx.x; // 128
  float s=b1[j];
  for(int k=0;k<64;k++) s+=W1[(64+k)*128+j];
  badj[j]=s;
}

// ---------------- entity SpMM: agg = (A @ x) * v + boundary ----------------
__global__ __launch_bounds__(256) void k_spmm_ent(
    const float* __restrict__ x, const float* __restrict__ v,
    const int* __restrict__ rp, const int* __restrict__ col,
    const int* __restrict__ batch, float* __restrict__ agg, int N){
  int gw=blockIdx.x*4+(threadIdx.x>>6);
  int lane=threadIdx.x&63;
  if(gw>=N) return;
  int n=gw;
  int beg=rp[n], end=rp[n+1];
  float a0=0.f,a1=0.f,a2=0.f,a3=0.f;
  int e=beg;
  for(; e+2<=end; e+=2){
    int s0=col[e], s1=col[e+1];
    const float* r0=x+(i64)s0*256;
    const float* r1=x+(i64)s1*256;
    a0+=r0[lane];     a1+=r0[64+lane];
    a2+=r0[128+lane]; a3+=r0[192+lane];
    a0+=r1[lane];     a1+=r1[64+lane];
    a2+=r1[128+lane]; a3+=r1[192+lane];
  }
  if(e<end){
    const float* r0=x+(i64)col[e]*256;
    a0+=r0[lane]; a1+=r0[64+lane]; a2+=r0[128+lane]; a3+=r0[192+lane];
  }
  float vl=v[lane];
  #pragma unroll
  for(int b=0;b<4;b++){
    int h=batch[b*96], t=batch[b*96+1];
    float bnd=(n==h?1.f:0.f)-(n==t?1.f:0.f);
    float av=(b==0)?a0:(b==1)?a1:(b==2)?a2:a3;
    agg[((i64)n*4+b)*64+lane]=av*vl+bnd;
  }
}

// ---------------- relation SpMM, dirs d0..d0+gridDim.z-1, 4 edge-chunks, atomic into aggr ----------------
// aggr pre-filled with 1.0 (boundary_r); grid (256 rows, 4 chunks, ndir)
__global__ __launch_bounds__(256) void k_spmm_rel(
    const float* __restrict__ y, const float* __restrict__ relbuf, i64 rbs,
    const int* __restrict__ rp_rel, const int* __restrict__ col_rel,
    const int* __restrict__ rei, const int* __restrict__ ret,
    float* __restrict__ aggr, int d0, int ER){
  __shared__ float s_acc[4][4][64];
  int rr=blockIdx.x; int ch=blockIdx.y; int dz=blockIdx.z;
  int d=d0+dz;
  const float* rb=relbuf+(i64)dz*rbs;
  int tx=threadIdx.x; int ws=tx>>6; int lane=tx&63;
  int beg=rp_rel[d*257+rr], end=rp_rel[d*257+rr+1];
  int len=end-beg;
  int per=(len+3)>>2;
  int cb=beg+ch*per;
  int ce_=cb+per; if(ce_>end) ce_=end;
  int clen=ce_-cb; if(clen<0) clen=0;
  int perw=(clen+3)>>2;
  int e0=cb+ws*perw;
  int e1=e0+perw; if(e1>ce_) e1=ce_;
  const int* cidx=col_rel+(i64)d*ER;
  const int* srcA=rei+(i64)(2*d)*ER;
  const int* etA=ret+(i64)d*ER;
  float a0=0.f,a1=0.f,a2=0.f,a3=0.f;
  for(int e=e0;e<e1;++e){
    int eid=cidx[e];
    int s=srcA[eid], t=etA[eid];
    const float* yr=y+(i64)s*64;          // y layout [b][r][64], b stride 16384
    const float* rr2=rb+(i64)t*256;       // relbuf layout [n][b][64]
    a0+=yr[0*16384+lane]*rr2[     lane];
    a1+=yr[1*16384+lane]*rr2[ 64+lane];
    a2+=yr[2*16384+lane]*rr2[128+lane];
    a3+=yr[3*16384+lane]*rr2[192+lane];
  }
  s_acc[ws][0][lane]=a0; s_acc[ws][1][lane]=a1;
  s_acc[ws][2][lane]=a2; s_acc[ws][3][lane]=a3;
  __syncthreads();
  int b=ws;
  float vv=s_acc[0][b][lane]+s_acc[1][b][lane]+s_acc[2][b][lane]+s_acc[3][b][lane];
  atomicAdd(&aggr[((i64)(d*4+b)*256+rr)*64+lane],vv);
}

// ---------------- generic 64-col GEMM: out = op(relu?(in@W + bias)) ----------------
// OP: 0=write, 1=add residual then write
template<int KC, bool RELU, int OP>
__global__ __launch_bounds__(256,4) void k_gemm64(
    const float* __restrict__ inA, int lda,
    const float* __restrict__ inB, int ldb, i64 inBs,
    const float* __restrict__ W, int ldw, i64 Ws,
    const float* __restrict__ bias, i64 biasS,
    float* out, int ldo, i64 outS,
    const float* resid, int ldr,
    int rows){
  __shared__ float s_in[128*68];
  __shared__ float s_wt[64*68];
  int tx=threadIdx.x;
  int dy=blockIdx.y;
  const float* Wd=W+(i64)dy*Ws;
  const float* biasd=bias+(i64)dy*biasS;
  float* outd=out+(i64)dy*outS;
  int row0=blockIdx.x*128;
  int rslot=tx>>4, c0=tx&15;
  float acc[8][4];
  #pragma unroll
  for(int j=0;j<8;j++)
    #pragma unroll
    for(int cc=0;cc<4;cc++) acc[j][cc]=0.f;
  for(int kc=0;kc<KC;++kc){
    const float* in=(kc==0)?inA:(inB+(i64)dy*inBs);
    int ld=(kc==0)?lda:ldb;
    #pragma unroll
    for(int i=0;i<8;i++){
      int id=i*256+tx;
      int r=id>>4, k4=id&15;
      int gr=row0+r;
      float4 val=make_float4(0.f,0.f,0.f,0.f);
      if(gr<rows) val=*(const float4*)(in+(i64)gr*ld+k4*4);
      *(float4*)&s_in[r*68+k4*4]=val;
    }
    #pragma unroll
    for(int i=0;i<4;i++){
      int id=i*256+tx;
      int k=id>>4, c4=(id&15)*4;
      float4 wv=*(const float4*)(Wd+(i64)(kc*64+k)*ldw+c4);
      s_wt[(c4+0)*68+k]=wv.x; s_wt[(c4+1)*68+k]=wv.y;
      s_wt[(c4+2)*68+k]=wv.z; s_wt[(c4+3)*68+k]=wv.w;
    }
    __syncthreads();
    #pragma unroll 4
    for(int k4=0;k4<16;k4++){
      float4 wv[4];
      #pragma unroll
      for(int cc=0;cc<4;cc++) wv[cc]=*(const float4*)&s_wt[(c0+16*cc)*68+k4*4];
      #pragma unroll
      for(int j=0;j<8;j++){
        float4 iv=*(const float4*)&s_in[(rslot+16*j)*68+k4*4];
        #pragma unroll
        for(int cc=0;cc<4;cc++)
          acc[j][cc]+=iv.x*wv[cc].x+iv.y*wv[cc].y+iv.z*wv[cc].z+iv.w*wv[cc].w;
      }
    }
    __syncthreads();
  }
  #pragma unroll
  for(int j=0;j<8;j++){
    int r=row0+rslot+16*j;
    if(r>=rows) continue;
    #pragma unroll
    for(int cc=0;cc<4;cc++){
      int c=c0+16*cc;
      float vv=acc[j][cc]+biasd[c];
      if(RELU) vv=fmaxf(vv,0.f);
      if(OP==1) vv+=resid[(i64)r*ldr+c];
      outd[(i64)r*ldo+c]=vv;
    }
  }
}

// ---------------- fused 64->64(relu)->64 MLP, 128-row tiles, grid.y = MLP instance ----------------
// s_in is reused for the hidden activations after GEMM1 (52.2 KB LDS total).
__global__ __launch_bounds__(256,4) void k_mlp128(
    const float* __restrict__ in,
    const float* __restrict__ W1, i64 w1s,
    const float* __restrict__ b1, i64 b1s,
    const float* __restrict__ W2, i64 w2s,
    const float* __restrict__ b2, i64 b2s,
    float* __restrict__ out, i64 outs,
    int rows){
  __shared__ float s_in[128*68];
  __shared__ float s_wt[64*68];
  int tx=threadIdx.x;
  int dy=blockIdx.y;
  const float* W1d=W1+(i64)dy*w1s;
  const float* b1d=b1+(i64)dy*b1s;
  const float* W2d=W2+(i64)dy*w2s;
  const float* b2d=b2+(i64)dy*b2s;
  float* outd=out+(i64)dy*outs;
  int row0=blockIdx.x*128;
  int rslot=tx>>4, c0=tx&15;
  // stage input tile (128 x 64)
  #pragma unroll
  for(int i=0;i<8;i++){
    int id=i*256+tx;
    int r=id>>4, k4=id&15;
    int gr=row0+r;
    float4 val=make_float4(0.f,0.f,0.f,0.f);
    if(gr<rows) val=*(const float4*)(in+(i64)gr*64+k4*4);
    *(float4*)&s_in[r*68+k4*4]=val;
  }
  // stage W1 transposed: s_wt[c][k]
  #pragma unroll
  for(int i=0;i<4;i++){
    int id=i*256+tx;
    int k=id>>4, c4=(id&15)*4;
    float4 wv=*(const float4*)(W1d+(i64)k*64+c4);
    s_wt[(c4+0)*68+k]=wv.x; s_wt[(c4+1)*68+k]=wv.y;
    s_wt[(c4+2)*68+k]=wv.z; s_wt[(c4+3)*68+k]=wv.w;
  }
  __syncthreads();
  float acc[8][4];
  #pragma unroll
  for(int j=0;j<8;j++)
    #pragma unroll
    for(int cc=0;cc<4;cc++) acc[j][cc]=0.f;
  #pragma unroll 4
  for(int k4=0;k4<16;k4++){
    float4 wv[4];
    #pragma unroll
    for(int cc=0;cc<4;cc++) wv[cc]=*(const float4*)&s_wt[(c0+16*cc)*68+k4*4];
    #pragma unroll
    for(int j=0;j<8;j++){
      float4 iv=*(const float4*)&s_in[(rslot+16*j)*68+k4*4];
      #pragma unroll
      for(int cc=0;cc<4;cc++)
        acc[j][cc]+=iv.x*wv[cc].x+iv.y*wv[cc].y+iv.z*wv[cc].z+iv.w*wv[cc].w;
    }
  }
  __syncthreads();   // all reads of s_in / s_wt complete
  // hidden = relu(acc + b1) -> overwrite s_in; stage W2 -> s_wt
  #pragma unroll
  for(int j=0;j<8;j++)
    #pragma unroll
    for(int cc=0;cc<4;cc++)
      s_in[(rslot+16*j)*68+(c0+16*cc)]=fmaxf(acc[j][cc]+b1d[c0+16*cc],0.f);
  #pragma unroll
  for(int i=0;i<4;i++){
    int id=i*256+tx;
    int k=id>>4, c4=(id&15)*4;
    float4 wv=*(const float4*)(W2d+(i64)k*64+c4);
    s_wt[(c4+0)*68+k]=wv.x; s_wt[(c4+1)*68+k]=wv.y;
    s_wt[(c4+2)*68+k]=wv.z; s_wt[(c4+3)*68+k]=wv.w;
  }
  __syncthreads();
  #pragma unroll
  for(int j=0;j<8;j++)
    #pragma unroll
    for(int cc=0;cc<4;cc++) acc[j][cc]=0.f;
  #pragma unroll 4
  for(int k4=0;k4<16;k4++){
    float4 wv[4];
    #pragma unroll
    for(int cc=0;cc<4;cc++) wv[cc]=*(const float4*)&s_wt[(c0+16*cc)*68+k4*4];
    #pragma unroll
    for(int j=0;j<8;j++){
      float4 iv=*(const float4*)&s_in[(rslot+16*j)*68+k4*4];
      #pragma unroll
      for(int cc=0;cc<4;cc++)
        acc[j][cc]+=iv.x*wv[cc].x+iv.y*wv[cc].y+iv.z*wv[cc].z+iv.w*wv[cc].w;
    }
  }
  #pragma unroll
  for(int j=0;j<8;j++){
    int r=row0+rslot+16*j;
    if(r>=rows) continue;
    #pragma unroll
    for(int cc=0;cc<4;cc++)
      outd[(i64)r*64+c0+16*cc]=acc[j][cc]+b2d[c0+16*cc];
  }
}

// ---------------- fused final entity MLP: x <- mlp2_128([x|ones]) in-place ----------------
__global__ __launch_bounds__(256,4) void k_mlp_ent(
    float* __restrict__ x,
    const float* __restrict__ W1,   // (128,128) row-major; rows 0..63 used
    const float* __restrict__ badj, // 128 (ones-half + b1 folded)
    const float* __restrict__ W2,   // (128,64) row-major
    const float* __restrict__ b2o,  // 64
    int rows){
  __shared__ float s_in[64*68];
  __shared__ float s_h[64*68];
  __shared__ float s_wt[64*68];
  int tx=threadIdx.x;
  int row0=blockIdx.x*64;
  int rslot=tx>>4, c0=tx&15;
  #pragma unroll
  for(int i=0;i<4;i++){
    int id=i*256+tx;
    int r=id>>4, k4=id&15;
    int gr=row0+r;
    float4 val=make_float4(0.f,0.f,0.f,0.f);
    if(gr<rows) val=*(const float4*)(x+(i64)gr*64+k4*4);
    *(float4*)&s_in[r*68+k4*4]=val;
  }
  float accO[4][4];
  #pragma unroll
  for(int j=0;j<4;j++)
    #pragma unroll
    for(int cc=0;cc<4;cc++) accO[j][cc]=0.f;
  for(int half=0;half<2;++half){
    __syncthreads();
    #pragma unroll
    for(int i=0;i<4;i++){
      int id=i*256+tx;
      int k=id>>4, c4=(id&15)*4;
      float4 wv=*(const float4*)(W1+(i64)k*128+half*64+c4);
      s_wt[(c4+0)*68+k]=wv.x; s_wt[(c4+1)*68+k]=wv.y;
      s_wt[(c4+2)*68+k]=wv.z; s_wt[(c4+3)*68+k]=wv.w;
    }
    __syncthreads();
    float acc[4][4];
    #pragma unroll
    for(int j=0;j<4;j++)
      #pragma unroll
      for(int cc=0;cc<4;cc++) acc[j][cc]=0.f;
    #pragma unroll 4
    for(int k4=0;k4<16;k4++){
      float4 wv[4];
      #pragma unroll
      for(int cc=0;cc<4;cc++) wv[cc]=*(const float4*)&s_wt[(c0+16*cc)*68+k4*4];
      #pragma unroll
      for(int j=0;j<4;j++){
        float4 iv=*(const float4*)&s_in[(rslot+16*j)*68+k4*4];
        #pragma unroll
        for(int cc=0;cc<4;cc++)
          acc[j][cc]+=iv.x*wv[cc].x+iv.y*wv[cc].y+iv.z*wv[cc].z+iv.w*wv[cc].w;
      }
    }
    __syncthreads();
    #pragma unroll
    for(int j=0;j<4;j++)
      #pragma unroll
      for(int cc=0;cc<4;cc++)
        s_h[(rslot+16*j)*68+(c0+16*cc)]=fmaxf(acc[j][cc]+badj[half*64+c0+16*cc],0.f);
    #pragma unroll
    for(int i=0;i<4;i++){
      int id=i*256+tx;
      int k=id>>4, c4=(id&15)*4;
      float4 wv=*(const float4*)(W2+(i64)(half*64+k)*64+c4);
      s_wt[(c4+0)*68+k]=wv.x; s_wt[(c4+1)*68+k]=wv.y;
      s_wt[(c4+2)*68+k]=wv.z; s_wt[(c4+3)*68+k]=wv.w;
    }
    __syncthreads();
    #pragma unroll 4
    for(int k4=0;k4<16;k4++){
      float4 wv[4];
      #pragma unroll
      for(int cc=0;cc<4;cc++) wv[cc]=*(const float4*)&s_wt[(c0+16*cc)*68+k4*4];
      #pragma unroll
      for(int j=0;j<4;j++){
        float4 iv=*(const float4*)&s_h[(rslot+16*j)*68+k4*4];
        #pragma unroll
        for(int cc=0;cc<4;cc++)
          accO[j][cc]+=iv.x*wv[cc].x+iv.y*wv[cc].y+iv.z*wv[cc].z+iv.w*wv[cc].w;
      }
    }
  }
  #pragma unroll
  for(int j=0;j<4;j++){
    int r=row0+rslot+16*j;
    if(r>=rows) continue;
    #pragma unroll
    for(int cc=0;cc<4;cc++)
      x[(i64)r*64+c0+16*cc]=accO[j][cc]+b2o[c0+16*cc];
  }
}

// ---------------- y += sum of 4 per-direction hid buffers; reset aggr to 1.0 ----------------
__global__ void k_yupd_fill(float* __restrict__ y, const float* __restrict__ h,
                            float* __restrict__ aggr){
  int i=blockIdx.x*256+threadIdx.x;   // grid covers 262144
  if(i<65536) y[i]+=h[i]+h[65536+i]+h[131072+i]+h[196608+i];
  if(i<262144) aggr[i]=1.0f;
}

// ---------------- init y=1 and aggr=1 ----------------
__global__ void k_init_rel(float* __restrict__ y, float* __restrict__ aggr){
  int i=blockIdx.x*256+threadIdx.x;
  if(i<65536) y[i]=1.0f;
  if(i<262144) aggr[i]=1.0f;
}

// ---------------- final gather + trix MLP ----------------
__global__ __launch_bounds__(256) void k_trix(
    const float* __restrict__ y, const int* __restrict__ batch,
    const float* __restrict__ W1, const float* __restrict__ b1,
    const float* __restrict__ W2, const float* __restrict__ b2,
    float* __restrict__ out){
  __shared__ float s_w1[64*65];
  int tx=threadIdx.x;
  for(int i=tx;i<4096;i+=256){
    int k=i>>6, j=i&63;
    s_w1[k*65+j]=W1[i];
  }
  __syncthreads();
  int wave=tx>>6, lane=tx&63;
  for(int row=wave;row<128;row+=4){
    int b=row>>5, i=row&31;
    int ridx=batch[b*96+i*3+2];
    const float* f=y+((i64)b*256+ridx)*64;
    float hj=b1[lane];
    for(int k=0;k<64;k++) hj+=f[k]*s_w1[k*65+lane];
    hj=fmaxf(hj,0.f);
    float contrib=hj*W2[lane];
    for(int off=32;off;off>>=1) contrib+=__shfl_down(contrib,off);
    if(lane==0) out[row]=contrib+b2[0];
  }
}

extern "C" void kernel_launch(void* const* d_in, const int* in_sizes, int n_in,
                              void* d_out, int out_size, void* d_ws, size_t ws_size,
                              hipStream_t stream){
  const int* batch=(const int*)d_in[0];
  const int* eei  =(const int*)d_in[1];
  const int* rei  =(const int*)d_in[3];
  const int* ret  =(const int*)d_in[4];
  const float* entW1=(const float*)d_in[7];
  const float* entb1=(const float*)d_in[8];
  const float* entW2=(const float*)d_in[9];
  const float* entb2=(const float*)d_in[10];
  const float* entWl=(const float*)d_in[11];
  const float* entbl=(const float*)d_in[12];
  const float* relW1=(const float*)d_in[13];
  const float* relb1=(const float*)d_in[14];
  const float* relW2=(const float*)d_in[15];
  const float* relb2=(const float*)d_in[16];
  const float* relWl=(const float*)d_in[17];
  const float* relbl=(const float*)d_in[18];
  const float* mW1=(const float*)d_in[19];
  const float* mb1=(const float*)d_in[20];
  const float* mW2=(const float*)d_in[21];
  const float* mb2=(const float*)d_in[22];
  const float* tW1=(const float*)d_in[23];
  const float* tb1=(const float*)d_in[24];
  const float* tW2=(const float*)d_in[25];
  const float* tb2=(const float*)d_in[26];
  const int E =in_sizes[2];
  const int ER=in_sizes[4]/4;
  float* out=(float*)d_out;

  // workspace layout (floats)
  float* ws=(float*)d_ws;
  float* x     =ws;                   // 5,120,000  ([n][b][64]); becomes node_reps
  float* buf   =x+5120000;            // 5,120,000  entity agg; rel relbuf (dir A)
  float* aggr  =buf+5120000;          //   262,144  rel agg [d][b][256][64]
  float* hidr  =aggr+262144;          //   262,144  rel hid per-direction
  float* y     =hidr+262144;          //    65,536  [b][256][64]
  float* v     =y+65536;              //       256  (4 layers x 64)
  float* badj  =v+256;                //       128
  int* rp_ent =(int*)(badj+128);      // NN+1
  int* cur_ent=rp_ent+NN+1;           // NN
  int* col_ent=cur_ent+NN;            // E
  int* rp_rel =col_ent+E;             // 4*257
  int* cur_rel=rp_rel+4*257;          // 1024
  int* col_rel=cur_rel+1024;          // 4*ER
  // optional second-direction buffer, rounded up to a 16B boundary
  size_t buf2_off=((size_t)(col_rel+4*ER-(int*)d_ws)+3)&~(size_t)3;   // in 4B words
  float* buf2 =(float*)d_ws+buf2_off; // optional 5,120,000 (dir B), if ws allows

  size_t needed =(buf2_off)*4;
  size_t needed2=(buf2_off+(size_t)5120000)*4;
  if(ws_size<needed) return; // insufficient scratch; validation will flag
  const bool two=(ws_size>=needed2);   // constant per deployment -> graph-capture safe
  const i64 bufStride=(i64)(buf2-buf); // float stride between dir A and dir B buffers

  const int* esrc=eei;
  const int* edst=eei+E;

  // ---- CSR builds ----
  k_fill2i<<<CDIV(NN,256),256,0,stream>>>(cur_ent,NN,cur_rel,1024);
  k_hist_ent<<<CDIV(E,256),256,0,stream>>>(edst,cur_ent,E);
  k_scan_ent<<<1,1024,0,stream>>>(cur_ent,rp_ent,NN);
  k_fill_ent<<<CDIV(E,256),256,0,stream>>>(esrc,edst,cur_ent,col_ent,E);
  k_hist_rel<<<dim3(CDIV(ER,256),4),256,0,stream>>>(rei,cur_rel,ER);
  k_scan_rel<<<4,256,0,stream>>>(cur_rel,rp_rel);
  k_fill_rel<<<dim3(CDIV(ER,256),4),256,0,stream>>>(rei,cur_rel,col_rel,ER);

  // ---- precompute per-layer v and adjusted bias ----
  k_ventity_all<<<LLAY,64,0,stream>>>(entW1,entb1,entW2,entb2,v);
  k_badj<<<1,128,0,stream>>>(mW1,mb1,badj);

  // ---- entity stack ----
  k_init_x<<<CDIV(NN*64,256),256,0,stream>>>(x,batch,NN);
  for(int l=0;l<LLAY;l++){
    k_spmm_ent<<<CDIV(NN,4),256,0,stream>>>(x,v+(i64)l*64,rp_ent,col_ent,batch,buf,NN);
    k_gemm64<2,true,1><<<625,256,0,stream>>>(x,64, buf,64,0,
        entWl+(i64)l*8192,64,0, entbl+(i64)l*64,0, x,64,0, x,64, 80000);
  }
  // ---- final entity MLP (fused, in-place): x <- node_reps ----
  k_mlp_ent<<<1250,256,0,stream>>>(x,mW1,badj,mW2,mb2,80000);

  // ---- relation stack ----
  k_init_rel<<<1024,256,0,stream>>>(y,aggr);
  for(int l=0;l<LLAY;l++){
    if(two){
      for(int d=0;d<4;d+=2){
        k_mlp128<<<dim3(625,2),256,0,stream>>>(x,
            relW1+(i64)(d*LLAY+l)*4096,(i64)LLAY*4096,
            relb1+(i64)(d*LLAY+l)*64,(i64)LLAY*64,
            relW2+(i64)(d*LLAY+l)*4096,(i64)LLAY*4096,
            relb2+(i64)(d*LLAY+l)*64,(i64)LLAY*64,
            buf,bufStride, 80000);
        k_spmm_rel<<<dim3(256,4,2),256,0,stream>>>(y,buf,bufStride,
            rp_rel,col_rel,rei,ret,aggr,d,ER);
      }
    } else {
      for(int d=0;d<4;d++){
        k_mlp128<<<dim3(625,1),256,0,stream>>>(x,
            relW1+(i64)(d*LLAY+l)*4096,0,
            relb1+(i64)(d*LLAY+l)*64,0,
            relW2+(i64)(d*LLAY+l)*4096,0,
            relb2+(i64)(d*LLAY+l)*64,0,
            buf,0, 80000);
        k_spmm_rel<<<dim3(256,4,1),256,0,stream>>>(y,buf,0,
            rp_rel,col_rel,rei,ret,aggr,d,ER);
      }
    }
    k_gemm64<2,true,0><<<dim3(8,4),256,0,stream>>>(y,64, aggr,64,(i64)65536,
        relWl+(i64)l*8192,64,(i64)LLAY*8192, relbl+(i64)l*64,(i64)LLAY*64,
        hidr,64,(i64)65536, y,64, 1024);
    k_yupd_fill<<<1024,256,0,stream>>>(y,hidr,aggr);
  }

  // ---- score ----
  k_trix<<<1,256,0,stream>>>(y,batch,tW1,tb1,tW2,tb2,out);
}

// Round 7
// 1261.997 us; speedup vs baseline: 2.7308x; 1.0495x over previous
//
#include <hip/hip_runtime.h>

typedef long long i64;
#define CDIV(a,b) (((a)+(b)-1)/(b))

#define NN   20000
#define RRN  256
#define BB   4
#define LLAY 4

// ---------------- utility fills ----------------
__global__ void k_fillf(float* p, float v, int n){ int i=blockIdx.x*256+threadIdx.x; if(i<n) p[i]=v; }
__global__ void k_fill2i(int* p1, int n1, int* p2, int n2){
  int i=blockIdx.x*256+threadIdx.x;
  if(i<n1) p1[i]=0;
  if(i<n2) p2[i]=0;
}

// ---------------- CSR build: entity graph ----------------
__global__ void k_hist_ent(const int* __restrict__ dst, int* __restrict__ cnt, int E){
  int e=blockIdx.x*256+threadIdx.x; if(e<E) atomicAdd(&cnt[dst[e]],1);
}
__global__ void k_scan_ent(int* cnt_cur, int* rp, int n){
  __shared__ int sm[1024];
  __shared__ int carry;
  int tx=threadIdx.x;
  if(tx==0) carry=0;
  __syncthreads();
  for(int base=0;base<n;base+=1024){
    int i=base+tx;
    int val=(i<n)?cnt_cur[i]:0;
    sm[tx]=val; __syncthreads();
    for(int off=1;off<1024;off<<=1){
      int t=(tx>=off)?sm[tx-off]:0; __syncthreads();
      sm[tx]+=t; __syncthreads();
    }
    int excl=carry+sm[tx]-val;
    if(i<n){ rp[i]=excl; cnt_cur[i]=excl; }
    __syncthreads();
    if(tx==0) carry+=sm[1023];
    __syncthreads();
  }
  if(tx==0) rp[n]=carry;
}
__global__ void k_fill_ent(const int* __restrict__ src, const int* __restrict__ dst,
                           int* __restrict__ cur, int* __restrict__ colsrc, int E){
  int e=blockIdx.x*256+threadIdx.x;
  if(e<E){ int p=atomicAdd(&cur[dst[e]],1); colsrc[p]=src[e]; }
}

// ---------------- CSR build: relation graph (4 directions) ----------------
__global__ void k_hist_rel(const int* __restrict__ rei, int* __restrict__ cnt, int ER){
  int e=blockIdx.x*256+threadIdx.x; int d=blockIdx.y;
  if(e<ER) atomicAdd(&cnt[d*256 + rei[(i64)(2*d+1)*ER + e]],1);
}
__global__ void k_scan_rel(int* cnt_cur, int* rp){
  __shared__ int sm[256];
  int d=blockIdx.x, tx=threadIdx.x;
  int val=cnt_cur[d*256+tx];
  sm[tx]=val; __syncthreads();
  for(int off=1;off<256;off<<=1){
    int t=(tx>=off)?sm[tx-off]:0; __syncthreads();
    sm[tx]+=t; __syncthreads();
  }
  int excl=sm[tx]-val;
  rp[d*257+tx]=excl;
  cnt_cur[d*256+tx]=excl;
  if(tx==255) rp[d*257+256]=sm[255];
}
__global__ void k_fill_rel(const int* __restrict__ rei, int* __restrict__ cur,
                           int* __restrict__ colr, int ER){
  int e=blockIdx.x*256+threadIdx.x; int d=blockIdx.y;
  if(e<ER){
    int dst=rei[(i64)(2*d+1)*ER+e];
    int p=atomicAdd(&cur[d*256+dst],1);
    colr[d*ER+p]=e;
  }
}

// ---------------- x init (layout [n][b][64]) ----------------
__global__ void k_init_x(float* __restrict__ x, const int* __restrict__ batch, int N){
  int i=blockIdx.x*256+threadIdx.x;          // float4 index
  int total=N*64;
  if(i>=total) return;
  int n=i>>6; int b=(i>>4)&3;
  int h=batch[b*96], t=batch[b*96+1];
  float bnd=(n==h?1.f:0.f)-(n==t?1.f:0.f);
  ((float4*)x)[i]=make_float4(bnd,bnd,bnd,bnd);
}

// ---------------- all entity per-layer rel vectors: v[l] = mlp2_l(ones), grid=LLAY ----------------
__global__ void k_ventity_all(const float* __restrict__ W1, const float* __restrict__ b1,
                              const float* __restrict__ W2, const float* __restrict__ b2,
                              float* __restrict__ v){
  __shared__ float sh[64];
  int l=blockIdx.x;
  const float* W1l=W1+(i64)l*4096;
  const float* W2l=W2+(i64)l*4096;
  int j=threadIdx.x;
  float s=b1[l*64+j];
  for(int i=0;i<64;i++) s+=W1l[i*64+j];
  sh[j]=fmaxf(s,0.f);
  __syncthreads();
  float vd=b2[l*64+j];
  for(int k=0;k<64;k++) vd+=sh[k]*W2l[k*64+j];
  v[l*64+j]=vd;
}

// ---------------- adjusted bias for final MLP ([x|ones] @ W1) ----------------
__global__ void k_badj(const float* __restrict__ W1, const float* __restrict__ b1,
                       float* __restrict__ badj){
  int j=threadIdx.x; // 128
  float s=b1[j];
  for(int k=0;k<64;k++) s+=W1[(64+k)*128+j];
  badj[j]=s;
}

// ---------------- entity SpMM: agg = (A @ x) * v + boundary ----------------
// wave = 1 node; lane holds float4: b=lane>>4, ch=(lane&15)*4..+3
__global__ __launch_bounds__(256) void k_spmm_ent(
    const float* __restrict__ x, const float* __restrict__ v,
    const int* __restrict__ rp, const int* __restrict__ col,
    const int* __restrict__ batch, float* __restrict__ agg, int N){
  int n=blockIdx.x*4+(threadIdx.x>>6);
  int lane=threadIdx.x&63;
  if(n>=N) return;
  int beg=rp[n], end=rp[n+1];
  float4 a=make_float4(0.f,0.f,0.f,0.f);
  int e=beg;
  for(; e+4<=end; e+=4){
    int s0=col[e], s1=col[e+1], s2=col[e+2], s3=col[e+3];
    float4 r0=*(const float4*)&x[(i64)s0*256+lane*4];
    float4 r1=*(const float4*)&x[(i64)s1*256+lane*4];
    float4 r2=*(const float4*)&x[(i64)s2*256+lane*4];
    float4 r3=*(const float4*)&x[(i64)s3*256+lane*4];
    a.x+=r0.x+r1.x+r2.x+r3.x;
    a.y+=r0.y+r1.y+r2.y+r3.y;
    a.z+=r0.z+r1.z+r2.z+r3.z;
    a.w+=r0.w+r1.w+r2.w+r3.w;
  }
  for(; e<end; ++e){
    float4 r0=*(const float4*)&x[(i64)col[e]*256+lane*4];
    a.x+=r0.x; a.y+=r0.y; a.z+=r0.z; a.w+=r0.w;
  }
  int b=lane>>4;
  float4 v4=*(const float4*)&v[(lane&15)*4];
  int h=batch[b*96], t=batch[b*96+1];
  float bnd=(n==h?1.f:0.f)-(n==t?1.f:0.f);
  float4 o;
  o.x=a.x*v4.x+bnd; o.y=a.y*v4.y+bnd; o.z=a.z*v4.z+bnd; o.w=a.w*v4.w+bnd;
  *(float4*)&agg[(i64)n*256+lane*4]=o;
}

// ---------------- relation SpMM: block owns (row, dir); 4 waves split edges; no atomics ----------------
// aggr[((d*4+b)*256+rr)*64+ch] = 1.0 + sum_e y[b][src][ch]*rel[etype][b][ch]
__global__ __launch_bounds__(256) void k_spmm_rel(
    const float* __restrict__ y, const float* __restrict__ relbuf, i64 rbs,
    const int* __restrict__ rp_rel, const int* __restrict__ col_rel,
    const int* __restrict__ rei, const int* __restrict__ ret,
    float* __restrict__ aggr, int d0, int ER){
  __shared__ float4 s_acc[4][64];
  int rr=blockIdx.x; int dz=blockIdx.y; int d=d0+dz;
  const float* rb=relbuf+(i64)dz*rbs;
  int tx=threadIdx.x; int wsl=tx>>6; int lane=tx&63;
  int beg=rp_rel[d*257+rr], end=rp_rel[d*257+rr+1];
  int len=end-beg;
  int perw=(len+3)>>2;
  int e0=beg+wsl*perw;
  int e1=e0+perw; if(e1>end) e1=end;
  const int* cidx=col_rel+(i64)d*ER;
  const int* srcA=rei+(i64)(2*d)*ER;
  const int* etA=ret+(i64)d*ER;
  int b=lane>>4; int ch4=(lane&15)*4;
  float4 a=make_float4(0.f,0.f,0.f,0.f);
  int e=e0;
  for(; e+2<=e1; e+=2){
    int eA=cidx[e], eB=cidx[e+1];
    int sA=srcA[eA], tA=etA[eA];
    int sB=srcA[eB], tB=etA[eB];
    float4 yA=*(const float4*)&y[(i64)b*16384+(i64)sA*64+ch4];
    float4 rA=*(const float4*)&rb[(i64)tA*256+lane*4];
    float4 yB=*(const float4*)&y[(i64)b*16384+(i64)sB*64+ch4];
    float4 rB=*(const float4*)&rb[(i64)tB*256+lane*4];
    a.x+=yA.x*rA.x+yB.x*rB.x;
    a.y+=yA.y*rA.y+yB.y*rB.y;
    a.z+=yA.z*rA.z+yB.z*rB.z;
    a.w+=yA.w*rA.w+yB.w*rB.w;
  }
  if(e<e1){
    int eA=cidx[e];
    int sA=srcA[eA], tA=etA[eA];
    float4 yA=*(const float4*)&y[(i64)b*16384+(i64)sA*64+ch4];
    float4 rA=*(const float4*)&rb[(i64)tA*256+lane*4];
    a.x+=yA.x*rA.x; a.y+=yA.y*rA.y; a.z+=yA.z*rA.z; a.w+=yA.w*rA.w;
  }
  s_acc[wsl][lane]=a;
  __syncthreads();
  if(wsl==0){
    float4 p0=s_acc[0][lane], p1=s_acc[1][lane], p2=s_acc[2][lane], p3=s_acc[3][lane];
    float4 o;
    o.x=1.0f+p0.x+p1.x+p2.x+p3.x;
    o.y=1.0f+p0.y+p1.y+p2.y+p3.y;
    o.z=1.0f+p0.z+p1.z+p2.z+p3.z;
    o.w=1.0f+p0.w+p1.w+p2.w+p3.w;
    *(float4*)&aggr[((i64)(d*4+b)*256+rr)*64+ch4]=o;
  }
}

// ---------------- generic 64-col GEMM: out = op(relu?(in@W + bias)) ----------------
// OP: 0=write, 1=add residual then write
template<int KC, bool RELU, int OP>
__global__ __launch_bounds__(256,4) void k_gemm64(
    const float* __restrict__ inA, int lda,
    const float* __restrict__ inB, int ldb, i64 inBs,
    const float* __restrict__ W, int ldw, i64 Ws,
    const float* __restrict__ bias, i64 biasS,
    float* out, int ldo, i64 outS,
    const float* resid, int ldr,
    int rows){
  __shared__ float s_in[128*68];
  __shared__ float s_wt[64*68];
  int tx=threadIdx.x;
  int dy=blockIdx.y;
  const float* Wd=W+(i64)dy*Ws;
  const float* biasd=bias+(i64)dy*biasS;
  float* outd=out+(i64)dy*outS;
  int row0=blockIdx.x*128;
  int rslot=tx>>4, c0=tx&15;
  float acc[8][4];
  #pragma unroll
  for(int j=0;j<8;j++)
    #pragma unroll
    for(int cc=0;cc<4;cc++) acc[j][cc]=0.f;
  for(int kc=0;kc<KC;++kc){
    const float* in=(kc==0)?inA:(inB+(i64)dy*inBs);
    int ld=(kc==0)?lda:ldb;
    #pragma unroll
    for(int i=0;i<8;i++){
      int id=i*256+tx;
      int r=id>>4, k4=id&15;
      int gr=row0+r;
      float4 val=make_float4(0.f,0.f,0.f,0.f);
      if(gr<rows) val=*(const float4*)(in+(i64)gr*ld+k4*4);
      *(float4*)&s_in[r*68+k4*4]=val;
    }
    #pragma unroll
    for(int i=0;i<4;i++){
      int id=i*256+tx;
      int k=id>>4, c4=(id&15)*4;
      float4 wv=*(const float4*)(Wd+(i64)(kc*64+k)*ldw+c4);
      s_wt[(c4+0)*68+k]=wv.x; s_wt[(c4+1)*68+k]=wv.y;
      s_wt[(c4+2)*68+k]=wv.z; s_wt[(c4+3)*68+k]=wv.w;
    }
    __syncthreads();
    #pragma unroll 4
    for(int k4=0;k4<16;k4++){
      float4 wv[4];
      #pragma unroll
      for(int cc=0;cc<4;cc++) wv[cc]=*(const float4*)&s_wt[(c0+16*cc)*68+k4*4];
      #pragma unroll
      for(int j=0;j<8;j++){
        float4 iv=*(const float4*)&s_in[(rslot+16*j)*68+k4*4];
        #pragma unroll
        for(int cc=0;cc<4;cc++)
          acc[j][cc]+=iv.x*wv[cc].x+iv.y*wv[cc].y+iv.z*wv[cc].z+iv.w*wv[cc].w;
      }
    }
    __syncthreads();
  }
  #pragma unroll
  for(int j=0;j<8;j++){
    int r=row0+rslot+16*j;
    if(r>=rows) continue;
    #pragma unroll
    for(int cc=0;cc<4;cc++){
      int c=c0+16*cc;
      float vv=acc[j][cc]+biasd[c];
      if(RELU) vv=fmaxf(vv,0.f);
      if(OP==1) vv+=resid[(i64)r*ldr+c];
      outd[(i64)r*ldo+c]=vv;
    }
  }
}

// ---------------- fused 64->64(relu)->64 MLP, 128-row tiles, grid.y = MLP instance ----------------
__global__ __launch_bounds__(256,4) void k_mlp128(
    const float* __restrict__ in,
    const float* __restrict__ W1, i64 w1s,
    const float* __restrict__ b1, i64 b1s,
    const float* __restrict__ W2, i64 w2s,
    const float* __restrict__ b2, i64 b2s,
    float* __restrict__ out, i64 outs,
    int rows){
  __shared__ float s_in[128*68];
  __shared__ float s_wt[64*68];
  int tx=threadIdx.x;
  int dy=blockIdx.y;
  const float* W1d=W1+(i64)dy*w1s;
  const float* b1d=b1+(i64)dy*b1s;
  const float* W2d=W2+(i64)dy*w2s;
  const float* b2d=b2+(i64)dy*b2s;
  float* outd=out+(i64)dy*outs;
  int row0=blockIdx.x*128;
  int rslot=tx>>4, c0=tx&15;
  // stage input tile (128 x 64)
  #pragma unroll
  for(int i=0;i<8;i++){
    int id=i*256+tx;
    int r=id>>4, k4=id&15;
    int gr=row0+r;
    float4 val=make_float4(0.f,0.f,0.f,0.f);
    if(gr<rows) val=*(const float4*)(in+(i64)gr*64+k4*4);
    *(float4*)&s_in[r*68+k4*4]=val;
  }
  // stage W1 transposed: s_wt[c][k]
  #pragma unroll
  for(int i=0;i<4;i++){
    int id=i*256+tx;
    int k=id>>4, c4=(id&15)*4;
    float4 wv=*(const float4*)(W1d+(i64)k*64+c4);
    s_wt[(c4+0)*68+k]=wv.x; s_wt[(c4+1)*68+k]=wv.y;
    s_wt[(c4+2)*68+k]=wv.z; s_wt[(c4+3)*68+k]=wv.w;
  }
  __syncthreads();
  float acc[8][4];
  #pragma unroll
  for(int j=0;j<8;j++)
    #pragma unroll
    for(int cc=0;cc<4;cc++) acc[j][cc]=0.f;
  #pragma unroll 4
  for(int k4=0;k4<16;k4++){
    float4 wv[4];
    #pragma unroll
    for(int cc=0;cc<4;cc++) wv[cc]=*(const float4*)&s_wt[(c0+16*cc)*68+k4*4];
    #pragma unroll
    for(int j=0;j<8;j++){
      float4 iv=*(const float4*)&s_in[(rslot+16*j)*68+k4*4];
      #pragma unroll
      for(int cc=0;cc<4;cc++)
        acc[j][cc]+=iv.x*wv[cc].x+iv.y*wv[cc].y+iv.z*wv[cc].z+iv.w*wv[cc].w;
    }
  }
  __syncthreads();   // all reads of s_in / s_wt complete
  // hidden = relu(acc + b1) -> overwrite s_in; stage W2 -> s_wt
  #pragma unroll
  for(int j=0;j<8;j++)
    #pragma unroll
    for(int cc=0;cc<4;cc++)
      s_in[(rslot+16*j)*68+(c0+16*cc)]=fmaxf(acc[j][cc]+b1d[c0+16*cc],0.f);
  #pragma unroll
  for(int i=0;i<4;i++){
    int id=i*256+tx;
    int k=id>>4, c4=(id&15)*4;
    float4 wv=*(const float4*)(W2d+(i64)k*64+c4);
    s_wt[(c4+0)*68+k]=wv.x; s_wt[(c4+1)*68+k]=wv.y;
    s_wt[(c4+2)*68+k]=wv.z; s_wt[(c4+3)*68+k]=wv.w;
  }
  __syncthreads();
  #pragma unroll
  for(int j=0;j<8;j++)
    #pragma unroll
    for(int cc=0;cc<4;cc++) acc[j][cc]=0.f;
  #pragma unroll 4
  for(int k4=0;k4<16;k4++){
    float4 wv[4];
    #pragma unroll
    for(int cc=0;cc<4;cc++) wv[cc]=*(const float4*)&s_wt[(c0+16*cc)*68+k4*4];
    #pragma unroll
    for(int j=0;j<8;j++){
      float4 iv=*(const float4*)&s_in[(rslot+16*j)*68+k4*4];
      #pragma unroll
      for(int cc=0;cc<4;cc++)
        acc[j][cc]+=iv.x*wv[cc].x+iv.y*wv[cc].y+iv.z*wv[cc].z+iv.w*wv[cc].w;
    }
  }
  #pragma unroll
  for(int j=0;j<8;j++){
    int r=row0+rslot+16*j;
    if(r>=rows) continue;
    #pragma unroll
    for(int cc=0;cc<4;cc++)
      outd[(i64)r*64+c0+16*cc]=acc[j][cc]+b2d[c0+16*cc];
  }
}

// ---------------- fused final entity MLP: x <- mlp2_128([x|ones]) in-place ----------------
__global__ __launch_bounds__(256,4) void k_mlp_ent(
    float* __restrict__ x,
    const float* __restrict__ W1,   // (128,128) row-major; rows 0..63 used
    const float* __restrict__ badj, // 128 (ones-half + b1 folded)
    const float* __restrict__ W2,   // (128,64) row-major
    const float* __restrict__ b2o,  // 64
    int rows){
  __shared__ float s_in[64*68];
  __shared__ float s_h[64*68];
  __shared__ float s_wt[64*68];
  int tx=threadIdx.x;
  int row0=blockIdx.x*64;
  int rslot=tx>>4, c0=tx&15;
  #pragma unroll
  for(int i=0;i<4;i++){
    int id=i*256+tx;
    int r=id>>4, k4=id&15;
    int gr=row0+r;
    float4 val=make_float4(0.f,0.f,0.f,0.f);
    if(gr<rows) val=*(const float4*)(x+(i64)gr*64+k4*4);
    *(float4*)&s_in[r*68+k4*4]=val;
  }
  float accO[4][4];
  #pragma unroll
  for(int j=0;j<4;j++)
    #pragma unroll
    for(int cc=0;cc<4;cc++) accO[j][cc]=0.f;
  for(int half=0;half<2;++half){
    __syncthreads();
    #pragma unroll
    for(int i=0;i<4;i++){
      int id=i*256+tx;
      int k=id>>4, c4=(id&15)*4;
      float4 wv=*(const float4*)(W1+(i64)k*128+half*64+c4);
      s_wt[(c4+0)*68+k]=wv.x; s_wt[(c4+1)*68+k]=wv.y;
      s_wt[(c4+2)*68+k]=wv.z; s_wt[(c4+3)*68+k]=wv.w;
    }
    __syncthreads();
    float acc[4][4];
    #pragma unroll
    for(int j=0;j<4;j++)
      #pragma unroll
      for(int cc=0;cc<4;cc++) acc[j][cc]=0.f;
    #pragma unroll 4
    for(int k4=0;k4<16;k4++){
      float4 wv[4];
      #pragma unroll
      for(int cc=0;cc<4;cc++) wv[cc]=*(const float4*)&s_wt[(c0+16*cc)*68+k4*4];
      #pragma unroll
      for(int j=0;j<4;j++){
        float4 iv=*(const float4*)&s_in[(rslot+16*j)*68+k4*4];
        #pragma unroll
        for(int cc=0;cc<4;cc++)
          acc[j][cc]+=iv.x*wv[cc].x+iv.y*wv[cc].y+iv.z*wv[cc].z+iv.w*wv[cc].w;
      }
    }
    __syncthreads();
    #pragma unroll
    for(int j=0;j<4;j++)
      #pragma unroll
      for(int cc=0;cc<4;cc++)
        s_h[(rslot+16*j)*68+(c0+16*cc)]=fmaxf(acc[j][cc]+badj[half*64+c0+16*cc],0.f);
    #pragma unroll
    for(int i=0;i<4;i++){
      int id=i*256+tx;
      int k=id>>4, c4=(id&15)*4;
      float4 wv=*(const float4*)(W2+(i64)(half*64+k)*64+c4);
      s_wt[(c4+0)*68+k]=wv.x; s_wt[(c4+1)*68+k]=wv.y;
      s_wt[(c4+2)*68+k]=wv.z; s_wt[(c4+3)*68+k]=wv.w;
    }
    __syncthreads();
    #pragma unroll 4
    for(int k4=0;k4<16;k4++){
      float4 wv[4];
      #pragma unroll
      for(int cc=0;cc<4;cc++) wv[cc]=*(const float4*)&s_wt[(c0+16*cc)*68+k4*4];
      #pragma unroll
      for(int j=0;j<4;j++){
        float4 iv=*(const float4*)&s_h[(rslot+16*j)*68+k4*4];
        #pragma unroll
        for(int cc=0;cc<4;cc++)
          accO[j][cc]+=iv.x*wv[cc].x+iv.y*wv[cc].y+iv.z*wv[cc].z+iv.w*wv[cc].w;
      }
    }
  }
  #pragma unroll
  for(int j=0;j<4;j++){
    int r=row0+rslot+16*j;
    if(r>=rows) continue;
    #pragma unroll
    for(int cc=0;cc<4;cc++)
      x[(i64)r*64+c0+16*cc]=accO[j][cc]+b2o[c0+16*cc];
  }
}

// ---------------- y += sum of 4 per-direction hid buffers ----------------
__global__ void k_yupdate4(float* __restrict__ y, const float* __restrict__ h, int n){
  int i=blockIdx.x*256+threadIdx.x;
  if(i<n) y[i]+=h[i]+h[(i64)n+i]+h[(i64)2*n+i]+h[(i64)3*n+i];
}

// ---------------- final gather + trix MLP ----------------
__global__ __launch_bounds__(256) void k_trix(
    const float* __restrict__ y, const int* __restrict__ batch,
    const float* __restrict__ W1, const float* __restrict__ b1,
    const float* __restrict__ W2, const float* __restrict__ b2,
    float* __restrict__ out){
  __shared__ float s_w1[64*65];
  int tx=threadIdx.x;
  for(int i=tx;i<4096;i+=256){
    int k=i>>6, j=i&63;
    s_w1[k*65+j]=W1[i];
  }
  __syncthreads();
  int wave=tx>>6, lane=tx&63;
  for(int row=wave;row<128;row+=4){
    int b=row>>5, i=row&31;
    int ridx=batch[b*96+i*3+2];
    const float* f=y+((i64)b*256+ridx)*64;
    float hj=b1[lane];
    for(int k=0;k<64;k++) hj+=f[k]*s_w1[k*65+lane];
    hj=fmaxf(hj,0.f);
    float contrib=hj*W2[lane];
    for(int off=32;off;off>>=1) contrib+=__shfl_down(contrib,off);
    if(lane==0) out[row]=contrib+b2[0];
  }
}

extern "C" void kernel_launch(void* const* d_in, const int* in_sizes, int n_in,
                              void* d_out, int out_size, void* d_ws, size_t ws_size,
                              hipStream_t stream){
  const int* batch=(const int*)d_in[0];
  const int* eei  =(const int*)d_in[1];
  const int* rei  =(const int*)d_in[3];
  const int* ret  =(const int*)d_in[4];
  const float* entW1=(const float*)d_in[7];
  const float* entb1=(const float*)d_in[8];
  const float* entW2=(const float*)d_in[9];
  const float* entb2=(const float*)d_in[10];
  const float* entWl=(const float*)d_in[11];
  const float* entbl=(const float*)d_in[12];
  const float* relW1=(const float*)d_in[13];
  const float* relb1=(const float*)d_in[14];
  const float* relW2=(const float*)d_in[15];
  const float* relb2=(const float*)d_in[16];
  const float* relWl=(const float*)d_in[17];
  const float* relbl=(const float*)d_in[18];
  const float* mW1=(const float*)d_in[19];
  const float* mb1=(const float*)d_in[20];
  const float* mW2=(const float*)d_in[21];
  const float* mb2=(const float*)d_in[22];
  const float* tW1=(const float*)d_in[23];
  const float* tb1=(const float*)d_in[24];
  const float* tW2=(const float*)d_in[25];
  const float* tb2=(const float*)d_in[26];
  const int E =in_sizes[2];
  const int ER=in_sizes[4]/4;
  float* out=(float*)d_out;

  // workspace layout (floats)
  float* ws=(float*)d_ws;
  float* x     =ws;                   // 5,120,000  ([n][b][64]); becomes node_reps
  float* aggr  =x+5120000;            //   262,144  rel agg [d][b][256][64]
  float* hidr  =aggr+262144;          //   262,144  rel hid per-direction
  float* y     =hidr+262144;          //    65,536  [b][256][64]
  float* v     =y+65536;              //       256  (4 layers x 64)
  float* badj  =v+256;                //       128
  int* rp_ent =(int*)(badj+128);      // NN+1
  int* cur_ent=rp_ent+NN+1;           // NN
  int* col_ent=cur_ent+NN;            // E
  int* rp_rel =col_ent+E;             // 4*257
  int* cur_rel=rp_rel+4*257;          // 1024
  int* col_rel=cur_rel+1024;          // 4*ER
  // MLP output buffers (1, 2, or 4 directions), 16B-aligned
  size_t base_words=((size_t)(col_rel+4*ER-(int*)d_ws)+3)&~(size_t)3;
  float* bufR=(float*)d_ws+base_words;
  size_t avail=(ws_size/4>base_words)?(ws_size/4-base_words):0;
  const int nb = avail>=(size_t)4*5120000 ? 4 : avail>=(size_t)2*5120000 ? 2 :
                 avail>=(size_t)5120000 ? 1 : 0;
  if(nb==0) return; // insufficient scratch; validation will flag
  const i64 BSTRIDE=5120000;

  const int* esrc=eei;
  const int* edst=eei+E;

  // ---- CSR builds ----
  k_fill2i<<<CDIV(NN,256),256,0,stream>>>(cur_ent,NN,cur_rel,1024);
  k_hist_ent<<<CDIV(E,256),256,0,stream>>>(edst,cur_ent,E);
  k_scan_ent<<<1,1024,0,stream>>>(cur_ent,rp_ent,NN);
  k_fill_ent<<<CDIV(E,256),256,0,stream>>>(esrc,edst,cur_ent,col_ent,E);
  k_hist_rel<<<dim3(CDIV(ER,256),4),256,0,stream>>>(rei,cur_rel,ER);
  k_scan_rel<<<4,256,0,stream>>>(cur_rel,rp_rel);
  k_fill_rel<<<dim3(CDIV(ER,256),4),256,0,stream>>>(rei,cur_rel,col_rel,ER);

  // ---- precompute per-layer v and adjusted bias ----
  k_ventity_all<<<LLAY,64,0,stream>>>(entW1,entb1,entW2,entb2,v);
  k_badj<<<1,128,0,stream>>>(mW1,mb1,badj);

  // ---- entity stack ----
  k_init_x<<<CDIV(NN*64,256),256,0,stream>>>(x,batch,NN);
  for(int l=0;l<LLAY;l++){
    k_spmm_ent<<<CDIV(NN,4),256,0,stream>>>(x,v+(i64)l*64,rp_ent,col_ent,batch,bufR,NN);
    k_gemm64<2,true,1><<<625,256,0,stream>>>(x,64, bufR,64,0,
        entWl+(i64)l*8192,64,0, entbl+(i64)l*64,0, x,64,0, x,64, 80000);
  }
  // ---- final entity MLP (fused, in-place): x <- node_reps ----
  k_mlp_ent<<<1250,256,0,stream>>>(x,mW1,badj,mW2,mb2,80000);

  // ---- relation stack ----
  k_fillf<<<256,256,0,stream>>>(y,1.0f,65536);
  for(int l=0;l<LLAY;l++){
    for(int d0=0;d0<4;d0+=nb){
      int nd=(4-d0<nb)?(4-d0):nb;
      k_mlp128<<<dim3(625,nd),256,0,stream>>>(x,
          relW1+(i64)(d0*LLAY+l)*4096,(i64)LLAY*4096,
          relb1+(i64)(d0*LLAY+l)*64,(i64)LLAY*64,
          relW2+(i64)(d0*LLAY+l)*4096,(i64)LLAY*4096,
          relb2+(i64)(d0*LLAY+l)*64,(i64)LLAY*64,
          bufR,BSTRIDE, 80000);
      k_spmm_rel<<<dim3(256,nd),256,0,stream>>>(y,bufR,BSTRIDE,
          rp_rel,col_rel,rei,ret,aggr,d0,ER);
    }
    k_gemm64<2,true,0><<<dim3(8,4),256,0,stream>>>(y,64, aggr,64,(i64)65536,
        relWl+(i64)l*8192,64,(i64)LLAY*8192, relbl+(i64)l*64,(i64)LLAY*64,
        hidr,64,(i64)65536, y,64, 1024);
    k_yupdate4<<<256,256,0,stream>>>(y,hidr,65536);
  }

  // ---- score ----
  k_trix<<<1,256,0,stream>>>(y,batch,tW1,tb1,tW2,tb2,out);
}